// Round 3
// baseline (185.840 us; speedup 1.0000x reference)
//
#include <hip/hip_runtime.h>
#include <hip/hip_bf16.h>

typedef short short8 __attribute__((ext_vector_type(8)));
typedef short short4v __attribute__((ext_vector_type(4)));
typedef float f32x4 __attribute__((ext_vector_type(4)));

// Problem constants: B=2, T=2048, E=1024, H=16, D=64

__device__ __forceinline__ short bf16r(float f) {
  unsigned int u = __builtin_bit_cast(unsigned int, f);
  unsigned int r = (u + 0x7fffu + ((u >> 16) & 1u)) >> 16;   // RNE
  return (short)r;
}

// two f32 -> packed bf16x2 via HW converter (RNE)
__device__ __forceinline__ unsigned int cvtpk(float a, float b) {
  unsigned int r;
  asm("v_cvt_pk_bf16_f32 %0, %1, %2" : "=v"(r) : "v"(a), "v"(b));
  return r;
}

__device__ __forceinline__ float fast_exp2(float x) {
  return __builtin_amdgcn_exp2f(x);
}

__device__ __forceinline__ void gload_lds16(const void* g, void* l) {
  __builtin_amdgcn_global_load_lds(
      (const __attribute__((address_space(1))) unsigned int*)g,
      (__attribute__((address_space(3))) unsigned int*)l, 16, 0, 0);
}

// ---------------- fused prep: x->bf16, W->bf16, rope table ----------------
__global__ void prep_k(const float* __restrict__ x, const float* __restrict__ W,
                       short* __restrict__ xb, short* __restrict__ wb,
                       float2* __restrict__ tab) {
  int gid = blockIdx.x * 256 + threadIdx.x;
  if (gid < 1048576) {                       // x: 4194304 f32 as float4
    float4 v = reinterpret_cast<const float4*>(x)[gid];
    short4v o = { bf16r(v.x), bf16r(v.y), bf16r(v.z), bf16r(v.w) };
    reinterpret_cast<short4v*>(xb)[gid] = o;
  } else if (gid < 1835008) {                // W: 3145728 f32
    int i = gid - 1048576;
    float4 v = reinterpret_cast<const float4*>(W)[i];
    short4v o = { bf16r(v.x), bf16r(v.y), bf16r(v.z), bf16r(v.w) };
    reinterpret_cast<short4v*>(wb)[i] = o;
  } else if (gid < 1900544) {                // rope table: 2048*32
    int idx = gid - 1835008;
    int t = idx >> 5, j = idx & 31;
    float freq = 1.0f / powf(10000.0f, (float)j * (1.0f / 32.0f));
    float ang = (float)t * freq;
    tab[idx] = make_float2(cosf(ang), sinf(ang));
  }
}

// ---------------- QKV GEMM: C[4096,3072] = x @ W^T + b, fused RoPE + scatter ----------------
// Double-buffered 2-phase: STAGE(next) issued BEFORE compute(cur); one barrier/K-step.
// q -> [bh][t][d] bf16, pre-scaled by (1/8)*log2(e); k -> [bh][t][d]; v -> [bh][d][t] transposed.
__launch_bounds__(256, 2)
__global__ void qkv_gemm_k(const short* __restrict__ xb, const short* __restrict__ wb,
                           const float* __restrict__ bias, const float2* __restrict__ tab,
                           short* __restrict__ qb, short* __restrict__ kb, short* __restrict__ vb) {
  __shared__ short lA[2][128 * 64];
  __shared__ short lB[2][128 * 64];
  const int tid = threadIdx.x;
  const int l = tid & 63, w = tid >> 6;
  const int wr = w >> 1, wc = w & 1;
  const int l15 = l & 15, lg = l >> 4;

  int bid = blockIdx.x;
  int swz = (bid & 7) * 96 + (bid >> 3);   // 768 blocks, bijective XCD swizzle
  int tm = swz / 24, tn = swz % 24;

  f32x4 acc[4][4] = {};

  auto stage = [&](int buf, int kt) {
    const int k0 = kt * 64;
#pragma unroll
    for (int p = 0; p < 4; ++p) {
      int idx = p * 256 + tid;
      int row = idx >> 3, ch = idx & 7;
      int gch = ch ^ (row & 7);
      gload_lds16(xb + (tm * 128 + row) * 1024 + k0 + gch * 8, (char*)lA[buf] + idx * 16);
    }
#pragma unroll
    for (int p = 0; p < 4; ++p) {
      int idx = p * 256 + tid;
      int row = idx >> 3, ch = idx & 7;
      int gch = ch ^ (row & 7);
      gload_lds16(wb + (tn * 128 + row) * 1024 + k0 + gch * 8, (char*)lB[buf] + idx * 16);
    }
  };

  stage(0, 0);
  __syncthreads();

  for (int kt = 0; kt < 16; ++kt) {
    const int cur = kt & 1;
    if (kt < 15) stage(cur ^ 1, kt + 1);     // prefetch overlaps the MFMAs below
    const char* la = (const char*)lA[cur];
    const char* lb = (const char*)lB[cur];
#pragma unroll
    for (int kc = 0; kc < 2; ++kc) {
      short8 af[4], bfr[4];
#pragma unroll
      for (int m = 0; m < 4; ++m) {
        int row = wr * 64 + m * 16 + l15;
        int ch = (kc * 4 + lg) ^ (row & 7);
        af[m] = *reinterpret_cast<const short8*>(la + row * 128 + ch * 16);
      }
#pragma unroll
      for (int n = 0; n < 4; ++n) {
        int row = wc * 64 + n * 16 + l15;
        int ch = (kc * 4 + lg) ^ (row & 7);
        bfr[n] = *reinterpret_cast<const short8*>(lb + row * 128 + ch * 16);
      }
#pragma unroll
      for (int m = 0; m < 4; ++m)
#pragma unroll
        for (int n = 0; n < 4; ++n)
          acc[m][n] = __builtin_amdgcn_mfma_f32_16x16x32_bf16(af[m], bfr[n], acc[m][n], 0, 0, 0);
    }
    __syncthreads();   // drains prefetch vmcnt + compute lgkm; next tile ready
  }

  const int sec = tn >> 3;   // 0=q 1=k 2=v
#pragma unroll
  for (int m = 0; m < 4; ++m) {
#pragma unroll
    for (int n = 0; n < 4; ++n) {
      int gcol = tn * 128 + wc * 64 + n * 16 + l15;
      float bv = bias[gcol];
      int colin = gcol & 1023;
      int h = colin >> 6, d = colin & 63;
      f32x4 v = acc[m][n];
#pragma unroll
      for (int i = 0; i < 4; ++i) v[i] += bv;
      int rbase = tm * 128 + wr * 64 + m * 16 + lg * 4;
      if (sec == 2) {
        int b = rbase >> 11, t0 = rbase & 2047;   // 4 consecutive t, same b
        short4v sv = { bf16r(v[0]), bf16r(v[1]), bf16r(v[2]), bf16r(v[3]) };
        *reinterpret_cast<short4v*>(vb + (((b * 16 + h) * 64 + d) * 2048) + t0) = sv;
      } else {
        int j = d >> 1;
        bool odd = d & 1;
        short* dst = (sec == 0) ? qb : kb;
        float scale = (sec == 0) ? 0.18033688f : 1.0f;  // (1/8)*log2e folded into q
#pragma unroll
        for (int i = 0; i < 4; ++i) {
          int grow = rbase + i;
          int t = grow & 2047;
          float2 cs = tab[t * 32 + j];
          float part = __shfl_xor(v[i], 1);
          float nv = odd ? (cs.y * part + cs.x * v[i]) : (cs.x * v[i] - cs.y * part);
          int b = grow >> 11;
          dst[(((b * 16 + h) * 2048 + t) << 6) + d] = bf16r(nv * scale);
        }
      }
    }
  }
}

// ---------------- Flash attention, swapped-QK^T ----------------
// 4 waves x 16 q-rows = 64 q/block; KVBLK=64 double-buffered; grid (32, 32) = 4 blocks/CU.
__launch_bounds__(256, 4)
__global__ void attn_k(const short* __restrict__ qb, const short* __restrict__ kb,
                       const short* __restrict__ vtb, float* __restrict__ out) {
  __shared__ short lK[2][64 * 64];    // [kv][d], chunk-XOR swizzled via source
  __shared__ short lVT[2][64 * 64];   // [d][kv], chunk-XOR swizzled via source
  __shared__ short lP[4][16 * 64];    // per-wave P^T as [q][kv], chunk-XOR swizzled
  const int tid = threadIdx.x, l = tid & 63, w = tid >> 6;
  const int l15 = l & 15, lg = l >> 4;
  const int qt = blockIdx.x, bh = blockIdx.y;

  const short* kbase = kb + bh * 2048 * 64;
  const short* vtbase = vtb + bh * 64 * 2048;

  auto stageKV = [&](int buf, int kt) {
#pragma unroll
    for (int p = 0; p < 2; ++p) {
      int idx = p * 256 + tid;
      int srow = idx >> 3, sch = idx & 7;
      int gch = sch ^ (srow & 7);
      gload_lds16(kbase + (kt * 64 + srow) * 64 + gch * 8, (char*)lK[buf] + idx * 16);
      gload_lds16(vtbase + srow * 2048 + kt * 64 + gch * 8, (char*)lVT[buf] + idx * 16);
    }
  };

  // Q B-frag (lane l15 = q column), q pre-scaled by log2e/8
  const int q = qt * 64 + w * 16 + l15;
  const short* qptr = qb + (bh * 2048 + q) * 64;
  short8 qf[2];
  qf[0] = *reinterpret_cast<const short8*>(qptr + lg * 8);
  qf[1] = *reinterpret_cast<const short8*>(qptr + 32 + lg * 8);

  f32x4 o[4] = {};
  float mval = -1e30f, lval = 0.f;
  char* pw = (char*)lP[w];
  const int pbase = l15 * 128;

  stageKV(0, 0);
  __syncthreads();

  for (int kt = 0; kt < 32; ++kt) {
    const int cur = kt & 1;
    if (kt < 31) stageKV(cur ^ 1, kt + 1);
    const char* lk = (const char*)lK[cur];
    const char* lv = (const char*)lVT[cur];

    // S^T[kv][q] : A = K tile (4 m-subtiles), B = Q
    f32x4 s[4] = {};
    __builtin_amdgcn_s_setprio(1);
#pragma unroll
    for (int kc = 0; kc < 2; ++kc)
#pragma unroll
      for (int m = 0; m < 4; ++m) {
        int row = m * 16 + l15;
        short8 kf = *reinterpret_cast<const short8*>(lk + row * 128 + (((kc * 4 + lg) ^ (row & 7)) * 16));
        s[m] = __builtin_amdgcn_mfma_f32_16x16x32_bf16(kf, qf[kc], s[m], 0, 0, 0);
      }
    __builtin_amdgcn_s_setprio(0);

    // row max: 16 in-lane + 2 shuffles (this lane owns q = l15)
    float rm = s[0][0];
#pragma unroll
    for (int m = 0; m < 4; ++m)
#pragma unroll
      for (int i = 0; i < 4; ++i) rm = fmaxf(rm, s[m][i]);
    rm = fmaxf(rm, __shfl_xor(rm, 16));
    rm = fmaxf(rm, __shfl_xor(rm, 32));

    // defer-max (T13): only rescale when some row grew by > 8 (log2 units)
    if (!__all(rm <= mval + 8.0f)) {
      float mn = fmaxf(mval, rm);
      float corr = fast_exp2(mval - mn);
      mval = mn;
      lval *= corr;
#pragma unroll
      for (int dt = 0; dt < 4; ++dt)
#pragma unroll
        for (int i = 0; i < 4; ++i) o[dt][i] *= corr;
    }

    // P = 2^(S - m), row sum
    float rs = 0.f;
#pragma unroll
    for (int m = 0; m < 4; ++m)
#pragma unroll
      for (int i = 0; i < 4; ++i) {
        s[m][i] = fast_exp2(s[m][i] - mval);
        rs += s[m][i];
      }
    rs += __shfl_xor(rs, 16);
    rs += __shfl_xor(rs, 32);
    lval += rs;

    // pack bf16 pairs (HW cvt_pk) -> per-wave P^T[q][kv] (u32 writes, chunk-XOR swizzle)
#pragma unroll
    for (int m = 0; m < 4; ++m)
#pragma unroll
      for (int j = 0; j < 2; ++j) {
        unsigned int v32 = cvtpk(s[m][2 * j], s[m][2 * j + 1]);
        int kv = m * 16 + lg * 4 + 2 * j;
        *reinterpret_cast<unsigned int*>(
            pw + pbase + (((kv >> 3) ^ (l15 & 7)) * 16) + ((kv & 7) * 2)) = v32;
      }

    // O^T += V^T P^T
    __builtin_amdgcn_s_setprio(1);
#pragma unroll
    for (int kc = 0; kc < 2; ++kc) {
      short8 pf = *reinterpret_cast<const short8*>(
          pw + pbase + (((kc * 4 + lg) ^ (l15 & 7)) * 16));
#pragma unroll
      for (int dt = 0; dt < 4; ++dt) {
        int row = dt * 16 + l15;
        short8 vf = *reinterpret_cast<const short8*>(lv + row * 128 + (((kc * 4 + lg) ^ (row & 7)) * 16));
        o[dt] = __builtin_amdgcn_mfma_f32_16x16x32_bf16(vf, pf, o[dt], 0, 0, 0);
      }
    }
    __builtin_amdgcn_s_setprio(0);
    __syncthreads();   // next tile staged (vmcnt drained) + all waves done with cur
  }

  // epilogue: O^T C-frag col=q, row=d -> float4 stores
  float inv = 1.0f / lval;
  const int b = bh >> 4, h = bh & 15;
  float* op = out + ((b * 2048 + q) * 1024) + h * 64;
#pragma unroll
  for (int dt = 0; dt < 4; ++dt) {
    f32x4 r = { o[dt][0] * inv, o[dt][1] * inv, o[dt][2] * inv, o[dt][3] * inv };
    *reinterpret_cast<f32x4*>(op + dt * 16 + lg * 4) = r;
  }
}

// ---------------- launch ----------------
extern "C" void kernel_launch(void* const* d_in, const int* in_sizes, int n_in,
                              void* d_out, int out_size, void* d_ws, size_t ws_size,
                              hipStream_t stream) {
  const float* x    = (const float*)d_in[0];   // [2,2048,1024]
  const float* W    = (const float*)d_in[1];   // [3072,1024]
  const float* bias = (const float*)d_in[2];   // [3072]
  float* out = (float*)d_out;
  char* ws = (char*)d_ws;

  short*  xb   = (short*) (ws);                  //  8 MiB
  short*  wb   = (short*) (ws + 8388608);        //  6 MiB
  short*  qbuf = (short*) (ws + 14680064);       //  8 MiB q [bh][t][d] (pre-scaled)
  short*  kbuf = (short*) (ws + 23068672);       //  8 MiB k [bh][t][d]
  short*  vtbuf= (short*) (ws + 31457280);       //  8 MiB v TRANSPOSED [bh][d][t]
  float2* tab  = (float2*)(ws + 39845888);       //  512 KiB

  hipLaunchKernelGGL(prep_k, dim3(7424), dim3(256), 0, stream, x, W, xb, wb, tab);
  hipLaunchKernelGGL(qkv_gemm_k, dim3(768), dim3(256), 0, stream,
                     xb, wb, bias, tab, qbuf, kbuf, vtbuf);
  hipLaunchKernelGGL(attn_k, dim3(32, 32), dim3(256), 0, stream, qbuf, kbuf, vtbuf, out);
}

// Round 6
// 167.813 us; speedup vs baseline: 1.1074x; 1.1074x over previous
//
#include <hip/hip_runtime.h>
#include <hip/hip_bf16.h>

typedef short short8 __attribute__((ext_vector_type(8)));
typedef short short4v __attribute__((ext_vector_type(4)));
typedef float f32x4 __attribute__((ext_vector_type(4)));

// Problem constants: B=2, T=2048, E=1024, H=16, D=64

__device__ __forceinline__ short bf16r(float f) {
  unsigned int u = __builtin_bit_cast(unsigned int, f);
  unsigned int r = (u + 0x7fffu + ((u >> 16) & 1u)) >> 16;   // RNE
  return (short)r;
}

// two f32 -> packed bf16x2 via HW converter (RNE)
__device__ __forceinline__ unsigned int cvtpk(float a, float b) {
  unsigned int r;
  asm("v_cvt_pk_bf16_f32 %0, %1, %2" : "=v"(r) : "v"(a), "v"(b));
  return r;
}

__device__ __forceinline__ float fast_exp2(float x) {
  return __builtin_amdgcn_exp2f(x);
}

__device__ __forceinline__ void gload_lds16(const void* g, void* l) {
  __builtin_amdgcn_global_load_lds(
      (const __attribute__((address_space(1))) unsigned int*)g,
      (__attribute__((address_space(3))) unsigned int*)l, 16, 0, 0);
}

// ---------------- fused prep: x->bf16, W->bf16, rope table ----------------
__global__ void prep_k(const float* __restrict__ x, const float* __restrict__ W,
                       short* __restrict__ xb, short* __restrict__ wb,
                       float2* __restrict__ tab) {
  int gid = blockIdx.x * 256 + threadIdx.x;
  if (gid < 1048576) {                       // x: 4194304 f32 as float4
    float4 v = reinterpret_cast<const float4*>(x)[gid];
    short4v o = { bf16r(v.x), bf16r(v.y), bf16r(v.z), bf16r(v.w) };
    reinterpret_cast<short4v*>(xb)[gid] = o;
  } else if (gid < 1835008) {                // W: 3145728 f32
    int i = gid - 1048576;
    float4 v = reinterpret_cast<const float4*>(W)[i];
    short4v o = { bf16r(v.x), bf16r(v.y), bf16r(v.z), bf16r(v.w) };
    reinterpret_cast<short4v*>(wb)[i] = o;
  } else if (gid < 1900544) {                // rope table: 2048*32
    int idx = gid - 1835008;
    int t = idx >> 5, j = idx & 31;
    float freq = 1.0f / powf(10000.0f, (float)j * (1.0f / 32.0f));
    float ang = (float)t * freq;
    tab[idx] = make_float2(cosf(ang), sinf(ang));
  }
}

// ---------------- QKV GEMM: C[4096,3072] = x @ W^T + b, fused RoPE + scatter ----------------
// Single-buffered (m97 operating point: 32KB LDS, 3 blocks/CU).
// q -> [bh][t][d] bf16, pre-scaled by (1/8)*log2(e); k -> [bh][t][d]; v -> [bh][d][t] transposed
// (V tile transposed through LDS for contiguous writes).
__launch_bounds__(256, 3)
__global__ void qkv_gemm_k(const short* __restrict__ xb, const short* __restrict__ wb,
                           const float* __restrict__ bias, const float2* __restrict__ tab,
                           short* __restrict__ qb, short* __restrict__ kb, short* __restrict__ vb) {
  __shared__ short lsm[17408];               // 34 KB: lA | lB during loop, lT[128][136] in V epilogue
  short* lA = lsm;
  short* lB = lsm + 8192;
  const int tid = threadIdx.x;
  const int l = tid & 63, w = tid >> 6;
  const int wr = w >> 1, wc = w & 1;
  const int l15 = l & 15, lg = l >> 4;

  int bid = blockIdx.x;
  int swz = (bid & 7) * 96 + (bid >> 3);   // 768 blocks, bijective XCD swizzle
  int tm = swz / 24, tn = swz % 24;

  f32x4 acc[4][4] = {};

  for (int kt = 0; kt < 16; ++kt) {
    const int k0 = kt * 64;
    __syncthreads();
#pragma unroll
    for (int p = 0; p < 4; ++p) {
      int idx = p * 256 + tid;
      int row = idx >> 3, ch = idx & 7;
      int gch = ch ^ (row & 7);
      gload_lds16(xb + (tm * 128 + row) * 1024 + k0 + gch * 8, (char*)lA + idx * 16);
    }
#pragma unroll
    for (int p = 0; p < 4; ++p) {
      int idx = p * 256 + tid;
      int row = idx >> 3, ch = idx & 7;
      int gch = ch ^ (row & 7);
      gload_lds16(wb + (tn * 128 + row) * 1024 + k0 + gch * 8, (char*)lB + idx * 16);
    }
    __syncthreads();
#pragma unroll
    for (int kc = 0; kc < 2; ++kc) {
      short8 af[4], bfr[4];
#pragma unroll
      for (int m = 0; m < 4; ++m) {
        int row = wr * 64 + m * 16 + l15;
        int ch = (kc * 4 + lg) ^ (row & 7);
        af[m] = *reinterpret_cast<const short8*>((const char*)lA + row * 128 + ch * 16);
      }
#pragma unroll
      for (int n = 0; n < 4; ++n) {
        int row = wc * 64 + n * 16 + l15;
        int ch = (kc * 4 + lg) ^ (row & 7);
        bfr[n] = *reinterpret_cast<const short8*>((const char*)lB + row * 128 + ch * 16);
      }
#pragma unroll
      for (int m = 0; m < 4; ++m)
#pragma unroll
        for (int n = 0; n < 4; ++n)
          acc[m][n] = __builtin_amdgcn_mfma_f32_16x16x32_bf16(af[m], bfr[n], acc[m][n], 0, 0, 0);
    }
  }

  const int sec = tn >> 3;   // 0=q 1=k 2=v (block-uniform)
  if (sec == 2) {
    // ---- V: transpose tile through LDS, then contiguous writes to [bh][d][t] ----
    __syncthreads();                          // all waves done with lA/lB
    short* lT = lsm;                          // [128 d][136 t-stride] (16B-aligned rows)
#pragma unroll
    for (int m = 0; m < 4; ++m)
#pragma unroll
      for (int n = 0; n < 4; ++n) {
        int d_local = wc * 64 + n * 16 + l15;
        int t_local = wr * 64 + m * 16 + lg * 4;
        float bv = bias[tn * 128 + d_local];
        f32x4 v = acc[m][n];
        short4v sv = { bf16r(v[0] + bv), bf16r(v[1] + bv), bf16r(v[2] + bv), bf16r(v[3] + bv) };
        *reinterpret_cast<short4v*>(lT + d_local * 136 + t_local) = sv;
      }
    __syncthreads();
    int row = tid >> 1;                       // d_local 0..127
    int tp = (tid & 1) * 64;                  // t half (64 t-values per thread)
    int h = (tn & 7) * 2 + (row >> 6);
    int d = row & 63;
    int bb = tm >> 4;
    int t0 = (tm * 128) & 2047;
    short* dst = vb + (((bb * 16 + h) * 64 + d) * 2048) + t0 + tp;
    const short* srcl = lT + row * 136 + tp;
#pragma unroll
    for (int c = 0; c < 8; ++c)
      *reinterpret_cast<short8*>(dst + c * 8) = *reinterpret_cast<const short8*>(srcl + c * 8);
  } else {
    // ---- Q/K: bias + RoPE + scatter ----
    short* dst = (sec == 0) ? qb : kb;
    float scale = (sec == 0) ? 0.18033688f : 1.0f;  // (1/8)*log2e folded into q
#pragma unroll
    for (int m = 0; m < 4; ++m) {
#pragma unroll
      for (int n = 0; n < 4; ++n) {
        int gcol = tn * 128 + wc * 64 + n * 16 + l15;
        float bv = bias[gcol];
        int colin = gcol & 1023;
        int h = colin >> 6, d = colin & 63;
        int j = d >> 1;
        bool odd = d & 1;
        f32x4 v = acc[m][n];
#pragma unroll
        for (int i = 0; i < 4; ++i) v[i] += bv;
        int rbase = tm * 128 + wr * 64 + m * 16 + lg * 4;
#pragma unroll
        for (int i = 0; i < 4; ++i) {
          int grow = rbase + i;
          int t = grow & 2047;
          float2 cs = tab[t * 32 + j];
          float part = __shfl_xor(v[i], 1);
          float nv = odd ? (cs.y * part + cs.x * v[i]) : (cs.x * v[i] - cs.y * part);
          int b = grow >> 11;
          dst[(((b * 16 + h) * 2048 + t) << 6) + d] = bf16r(nv * scale);
        }
      }
    }
  }
}

// ---------------- Flash attention, swapped-QK^T ----------------
// 4 waves x 16 q-rows = 64 q/block; KVBLK=64 double-buffered.
// Grid 1024 linear, decoded so XCD (id&7) owns bh in [4*xcd, 4*xcd+4):
// per-XCD KV working set = 4 x 512KB = 2MB < 4MB L2 -> staging loads become L2 hits.
__launch_bounds__(256, 4)
__global__ void attn_k(const short* __restrict__ qb, const short* __restrict__ kb,
                       const short* __restrict__ vtb, float* __restrict__ out) {
  __shared__ short lK[2][64 * 64];    // [kv][d], chunk-XOR swizzled via source
  __shared__ short lVT[2][64 * 64];   // [d][kv], chunk-XOR swizzled via source
  __shared__ short lP[4][16 * 64];    // per-wave P^T as [q][kv], chunk-XOR swizzled
  const int tid = threadIdx.x, l = tid & 63, w = tid >> 6;
  const int l15 = l & 15, lg = l >> 4;

  const int id = blockIdx.x;
  const int bh = (id & 7) * 4 + ((id >> 3) & 3);
  const int qt = id >> 5;

  const short* kbase = kb + bh * 2048 * 64;
  const short* vtbase = vtb + bh * 64 * 2048;

  auto stageKV = [&](int buf, int kt) {
#pragma unroll
    for (int p = 0; p < 2; ++p) {
      int idx = p * 256 + tid;
      int srow = idx >> 3, sch = idx & 7;
      int gch = sch ^ (srow & 7);
      gload_lds16(kbase + (kt * 64 + srow) * 64 + gch * 8, (char*)lK[buf] + idx * 16);
      gload_lds16(vtbase + srow * 2048 + kt * 64 + gch * 8, (char*)lVT[buf] + idx * 16);
    }
  };

  // Q B-frag (lane l15 = q column), q pre-scaled by log2e/8
  const int q = qt * 64 + w * 16 + l15;
  const short* qptr = qb + (bh * 2048 + q) * 64;
  short8 qf[2];
  qf[0] = *reinterpret_cast<const short8*>(qptr + lg * 8);
  qf[1] = *reinterpret_cast<const short8*>(qptr + 32 + lg * 8);

  f32x4 o[4] = {};
  float mval = -1e30f, lval = 0.f;
  char* pw = (char*)lP[w];
  const int pbase = l15 * 128;

  stageKV(0, 0);
  __syncthreads();

  for (int kt = 0; kt < 32; ++kt) {
    const int cur = kt & 1;
    if (kt < 31) stageKV(cur ^ 1, kt + 1);
    const char* lk = (const char*)lK[cur];
    const char* lv = (const char*)lVT[cur];

    // S^T[kv][q] : A = K tile (4 m-subtiles), B = Q
    f32x4 s[4] = {};
    __builtin_amdgcn_s_setprio(1);
#pragma unroll
    for (int kc = 0; kc < 2; ++kc)
#pragma unroll
      for (int m = 0; m < 4; ++m) {
        int row = m * 16 + l15;
        short8 kf = *reinterpret_cast<const short8*>(lk + row * 128 + (((kc * 4 + lg) ^ (row & 7)) * 16));
        s[m] = __builtin_amdgcn_mfma_f32_16x16x32_bf16(kf, qf[kc], s[m], 0, 0, 0);
      }
    __builtin_amdgcn_s_setprio(0);

    // row max: 16 in-lane + 2 shuffles (this lane owns q = l15)
    float rm = s[0][0];
#pragma unroll
    for (int m = 0; m < 4; ++m)
#pragma unroll
      for (int i = 0; i < 4; ++i) rm = fmaxf(rm, s[m][i]);
    rm = fmaxf(rm, __shfl_xor(rm, 16));
    rm = fmaxf(rm, __shfl_xor(rm, 32));

    // defer-max (T13): only rescale when some row grew by > 8 (log2 units)
    if (!__all(rm <= mval + 8.0f)) {
      float mn = fmaxf(mval, rm);
      float corr = fast_exp2(mval - mn);
      mval = mn;
      lval *= corr;
#pragma unroll
      for (int dt = 0; dt < 4; ++dt)
#pragma unroll
        for (int i = 0; i < 4; ++i) o[dt][i] *= corr;
    }

    // P = 2^(S - m), row sum
    float rs = 0.f;
#pragma unroll
    for (int m = 0; m < 4; ++m)
#pragma unroll
      for (int i = 0; i < 4; ++i) {
        s[m][i] = fast_exp2(s[m][i] - mval);
        rs += s[m][i];
      }
    rs += __shfl_xor(rs, 16);
    rs += __shfl_xor(rs, 32);
    lval += rs;

    // pack bf16 pairs (HW cvt_pk) -> per-wave P^T[q][kv] (u32 writes, chunk-XOR swizzle)
#pragma unroll
    for (int m = 0; m < 4; ++m)
#pragma unroll
      for (int j = 0; j < 2; ++j) {
        unsigned int v32 = cvtpk(s[m][2 * j], s[m][2 * j + 1]);
        int kv = m * 16 + lg * 4 + 2 * j;
        *reinterpret_cast<unsigned int*>(
            pw + pbase + (((kv >> 3) ^ (l15 & 7)) * 16) + ((kv & 7) * 2)) = v32;
      }

    // O^T += V^T P^T
    __builtin_amdgcn_s_setprio(1);
#pragma unroll
    for (int kc = 0; kc < 2; ++kc) {
      short8 pf = *reinterpret_cast<const short8*>(
          pw + pbase + (((kc * 4 + lg) ^ (l15 & 7)) * 16));
#pragma unroll
      for (int dt = 0; dt < 4; ++dt) {
        int row = dt * 16 + l15;
        short8 vf = *reinterpret_cast<const short8*>(lv + row * 128 + (((kc * 4 + lg) ^ (row & 7)) * 16));
        o[dt] = __builtin_amdgcn_mfma_f32_16x16x32_bf16(vf, pf, o[dt], 0, 0, 0);
      }
    }
    __builtin_amdgcn_s_setprio(0);
    __syncthreads();   // next tile staged (vmcnt drained) + all waves done with cur
  }

  // epilogue: O^T C-frag col=q, row=d -> float4 stores
  float inv = 1.0f / lval;
  const int b = bh >> 4, h = bh & 15;
  float* op = out + ((b * 2048 + q) * 1024) + h * 64;
#pragma unroll
  for (int dt = 0; dt < 4; ++dt) {
    f32x4 r = { o[dt][0] * inv, o[dt][1] * inv, o[dt][2] * inv, o[dt][3] * inv };
    *reinterpret_cast<f32x4*>(op + dt * 16 + lg * 4) = r;
  }
}

// ---------------- launch ----------------
extern "C" void kernel_launch(void* const* d_in, const int* in_sizes, int n_in,
                              void* d_out, int out_size, void* d_ws, size_t ws_size,
                              hipStream_t stream) {
  const float* x    = (const float*)d_in[0];   // [2,2048,1024]
  const float* W    = (const float*)d_in[1];   // [3072,1024]
  const float* bias = (const float*)d_in[2];   // [3072]
  float* out = (float*)d_out;
  char* ws = (char*)d_ws;

  short*  xb   = (short*) (ws);                  //  8 MiB
  short*  wb   = (short*) (ws + 8388608);        //  6 MiB
  short*  qbuf = (short*) (ws + 14680064);       //  8 MiB q [bh][t][d] (pre-scaled)
  short*  kbuf = (short*) (ws + 23068672);       //  8 MiB k [bh][t][d]
  short*  vtbuf= (short*) (ws + 31457280);       //  8 MiB v TRANSPOSED [bh][d][t]
  float2* tab  = (float2*)(ws + 39845888);       //  512 KiB

  hipLaunchKernelGGL(prep_k, dim3(7424), dim3(256), 0, stream, x, W, xb, wb, tab);
  hipLaunchKernelGGL(qkv_gemm_k, dim3(768), dim3(256), 0, stream,
                     xb, wb, bias, tab, qbuf, kbuf, vtbuf);
  hipLaunchKernelGGL(attn_k, dim3(1024), dim3(256), 0, stream, qbuf, kbuf, vtbuf, out);
}